// Round 11
// baseline (643.988 us; speedup 1.0000x reference)
//
#include <hip/hip_runtime.h>

// SimpleGRU scan: B=2048 seqs, T=2048 steps, H=32, O=2, fp32 backbone.
// Round-11: R8 base (full-K 2-batch/wave, 1024 waves, one-time weight pin —
// R10 proved in-loop pinning backfires: issue 352->386) with the h-exchange
// moved OFF memory entirely:
//   R8 measured wall 525 = issue 352 + 173 exposed, the 173 being
//   cvt -> ds_write -> lgkmcnt-drain (barrier) -> ds_read (~2 LDS latencies).
//   Fix: ds_bpermute_b32 reads partner lanes' REGISTERS via the crossbar --
//   no LDS storage, no write/read serialization, no barriers. Lane pairs
//   (j, j^1) pack (h_j, h_j^1) as f16x2 via DPP quad_perm swap + one
//   v_perm_b32 (loop-invariant selector), then 16 independent bpermutes
//   (base g*128, offset 8p) gather all 16 h-pairs for the next step.
//   Per-step wave_barriers deleted -> recurrence is pure dataflow.
// Plus: direct per-gate rcp sigmoids (-2 muls on critical r path, +1 trans
// issue). x stays in chunked LDS (barriers only at 32-step boundaries).

typedef _Float16 f16x2 __attribute__((ext_vector_type(2)));

__device__ __forceinline__ float fdot2(int a, int b, float c) {
    return __builtin_amdgcn_fdot2(__builtin_bit_cast(f16x2, a),
                                  __builtin_bit_cast(f16x2, b), c, false);
}

__device__ __forceinline__ int pack_pair(float a, float b) {
    f16x2 p;
    p.x = (_Float16)a;
    p.y = (_Float16)b;
    return __builtin_bit_cast(int, p);
}

__global__ __launch_bounds__(64, 1)
void gru_scan_kernel(const float* __restrict__ x,      // [B,T]
                     const float* __restrict__ w_ih,   // [96,1]
                     const float* __restrict__ w_hh,   // [96,32]
                     const float* __restrict__ b_ih,   // [96]
                     const float* __restrict__ b_hh,   // [96]
                     const float* __restrict__ head_w, // [2,32]
                     const float* __restrict__ head_b, // [2]
                     float* __restrict__ out,          // [B,2]
                     int T)
{
    const int l = (int)threadIdx.x;
    const int g = l >> 5;   // batch slot within wave
    const int j = l & 31;   // gate/hidden row
    const int b = (int)blockIdx.x * 2 + g;

    __shared__ float hf_s[2][32];                   // fp32 h for head only
    __shared__ __align__(16) float x_s[2][2][32];   // [group][buf][step]

    // ---- per-lane weights: rows j (r), 32+j (z), 64+j (n), full K=32,
    // as 16 f16x2 pairs per gate = 48 int regs, one-time pin (R8 config) ----
    int wR[16], wZ[16], wN[16];
    {
        const float* pR = w_hh + (     j) * 32;
        const float* pZ = w_hh + (32 + j) * 32;
        const float* pN = w_hh + (64 + j) * 32;
#pragma unroll
        for (int q = 0; q < 16; ++q) {
            wR[q] = pack_pair(pR[2*q], pR[2*q+1]);
            wZ[q] = pack_pair(pZ[2*q], pZ[2*q+1]);
            wN[q] = pack_pair(pN[2*q], pN[2*q+1]);
        }
    }
#pragma unroll
    for (int q = 0; q < 16; ++q) {
        asm volatile("" : "+v"(wR[q]), "+v"(wZ[q]), "+v"(wN[q]));
    }

    // full-K: every lane computes complete dots -> plain per-row seeds
    const float wihr = w_ih[j];
    const float wihz = w_ih[32 + j];
    const float wihn = w_ih[64 + j];
    const float br   = b_ih[j]      + b_hh[j];
    const float bz   = b_ih[32 + j] + b_hh[32 + j];
    const float bni  = b_ih[64 + j];
    const float bnh  = b_hh[64 + j];

    // pack selector (loop-invariant): result = f16x2(h_{j&~1}, h_{j|1})
    // v_perm pool: bytes 0-3 = oth (src1), bytes 4-7 = own (src0)
    const unsigned int psel = (j & 1) ? 0x05040100u : 0x01000504u;
    const int bbase = g * 128;    // bpermute byte base for this group

    const float* xrow   = x + (size_t)b * (size_t)T;
    const int    nchunk = T >> 5;   // 32-step chunks (T=2048 -> 64)

    float h = 0.0f;
    // h == 0 -> all packed h-pairs are 0
    int P0=0,P1=0,P2=0,P3=0,P4=0,P5=0,P6=0,P7=0;
    int P8=0,P9=0,P10=0,P11=0,P12=0,P13=0,P14=0,P15=0;

    x_s[g][0][j] = xrow[j];
    float xnext  = (nchunk > 1) ? xrow[32 + j] : 0.0f;
    __builtin_amdgcn_wave_barrier();

    for (int c = 0; c < nchunk; ++c) {
        const int buf = c & 1;
        const float* xs = &x_s[g][buf][0];
#pragma unroll 4
        for (int s = 0; s < 32; ++s) {
            const float xv = xs[s];                  // broadcast b32

            // 4 chains of 4 dot2 per gate (16 pairs = full K=32)
            float rA = fdot2(P0, wR[ 0], fmaf(xv, wihr, br));
            float zA = fdot2(P0, wZ[ 0], fmaf(xv, wihz, bz));
            float nA = fdot2(P0, wN[ 0], bnh);
            rA = fdot2(P1, wR[ 1], rA); zA = fdot2(P1, wZ[ 1], zA); nA = fdot2(P1, wN[ 1], nA);
            rA = fdot2(P2, wR[ 2], rA); zA = fdot2(P2, wZ[ 2], zA); nA = fdot2(P2, wN[ 2], nA);
            rA = fdot2(P3, wR[ 3], rA); zA = fdot2(P3, wZ[ 3], zA); nA = fdot2(P3, wN[ 3], nA);

            float rB = fdot2(P4, wR[ 4], 0.0f);
            float zB = fdot2(P4, wZ[ 4], 0.0f);
            float nB = fdot2(P4, wN[ 4], 0.0f);
            rB = fdot2(P5, wR[ 5], rB); zB = fdot2(P5, wZ[ 5], zB); nB = fdot2(P5, wN[ 5], nB);
            rB = fdot2(P6, wR[ 6], rB); zB = fdot2(P6, wZ[ 6], zB); nB = fdot2(P6, wN[ 6], nB);
            rB = fdot2(P7, wR[ 7], rB); zB = fdot2(P7, wZ[ 7], zB); nB = fdot2(P7, wN[ 7], nB);

            float rC = fdot2(P8, wR[ 8], 0.0f);
            float zC = fdot2(P8, wZ[ 8], 0.0f);
            float nC = fdot2(P8, wN[ 8], 0.0f);
            rC = fdot2(P9,  wR[ 9], rC); zC = fdot2(P9,  wZ[ 9], zC); nC = fdot2(P9,  wN[ 9], nC);
            rC = fdot2(P10, wR[10], rC); zC = fdot2(P10, wZ[10], zC); nC = fdot2(P10, wN[10], nC);
            rC = fdot2(P11, wR[11], rC); zC = fdot2(P11, wZ[11], zC); nC = fdot2(P11, wN[11], nC);

            float rD = fdot2(P12, wR[12], 0.0f);
            float zD = fdot2(P12, wZ[12], 0.0f);
            float nD = fdot2(P12, wN[12], 0.0f);
            rD = fdot2(P13, wR[13], rD); zD = fdot2(P13, wZ[13], zD); nD = fdot2(P13, wN[13], nD);
            rD = fdot2(P14, wR[14], rD); zD = fdot2(P14, wZ[14], zD); nD = fdot2(P14, wN[14], nD);
            rD = fdot2(P15, wR[15], rD); zD = fdot2(P15, wZ[15], zD); nD = fdot2(P15, wN[15], nD);

            const float rp = (rA + rB) + (rC + rD);
            const float zp = (zA + zB) + (zC + zD);
            const float np = (nA + nB) + (nC + nD);

            // direct-rcp sigmoids (r is on the critical path; z is late)
            const float er = __builtin_amdgcn_exp2f(rp * -1.44269504088896f);
            const float r  = __builtin_amdgcn_rcpf(1.0f + er);
            const float ez = __builtin_amdgcn_exp2f(zp * -1.44269504088896f);
            const float z  = __builtin_amdgcn_rcpf(1.0f + ez);

            // n = tanh(xn + r*np)
            const float xn = fmaf(xv, wihn, bni);
            const float u  = fmaf(r, np, xn);
            const float et = __builtin_amdgcn_exp2f(u * 2.88539008177793f);
            const float ti = __builtin_amdgcn_rcpf(1.0f + et);
            const float n  = fmaf(-2.0f, ti, 1.0f);

            h = fmaf(z, h - n, n);                   // (1-z)*n + z*h

            // ---- h exchange: register crossbar, no LDS memory ----
            const int own = (int)(unsigned int)
                __builtin_bit_cast(unsigned short, (_Float16)h);
            const int oth = __builtin_amdgcn_update_dpp(own, own, 0xB1,
                                                        0xF, 0xF, true);
            // pk = f16x2(h_{j&~1}, h_{j|1}) — same value in lanes j, j^1
            const int pk = (int)__builtin_amdgcn_perm(
                (unsigned int)own, (unsigned int)oth, psel);
            P0  = __builtin_amdgcn_ds_bpermute(bbase +   0, pk);
            P1  = __builtin_amdgcn_ds_bpermute(bbase +   8, pk);
            P2  = __builtin_amdgcn_ds_bpermute(bbase +  16, pk);
            P3  = __builtin_amdgcn_ds_bpermute(bbase +  24, pk);
            P4  = __builtin_amdgcn_ds_bpermute(bbase +  32, pk);
            P5  = __builtin_amdgcn_ds_bpermute(bbase +  40, pk);
            P6  = __builtin_amdgcn_ds_bpermute(bbase +  48, pk);
            P7  = __builtin_amdgcn_ds_bpermute(bbase +  56, pk);
            P8  = __builtin_amdgcn_ds_bpermute(bbase +  64, pk);
            P9  = __builtin_amdgcn_ds_bpermute(bbase +  72, pk);
            P10 = __builtin_amdgcn_ds_bpermute(bbase +  80, pk);
            P11 = __builtin_amdgcn_ds_bpermute(bbase +  88, pk);
            P12 = __builtin_amdgcn_ds_bpermute(bbase +  96, pk);
            P13 = __builtin_amdgcn_ds_bpermute(bbase + 104, pk);
            P14 = __builtin_amdgcn_ds_bpermute(bbase + 112, pk);
            P15 = __builtin_amdgcn_ds_bpermute(bbase + 120, pk);
        }
        if (c + 1 < nchunk) {
            x_s[g][1 - buf][j] = xnext;              // stage next chunk
            if (c + 2 < nchunk) xnext = xrow[(c + 2) * 32 + j];
            __builtin_amdgcn_wave_barrier();
        }
    }

    // ---- head: out[b,o] = head_b[o] + sum_k h[k]*head_w[o,k] (fp32 h) ----
    hf_s[g][j] = h;
    __builtin_amdgcn_wave_barrier();
    if (l < 4) {
        const int g2 = l >> 1, o = l & 1;
        float acc = head_b[o];
        const float* hw = head_w + o * 32;
#pragma unroll
        for (int k = 0; k < 32; ++k) acc = fmaf(hf_s[g2][k], hw[k], acc);
        out[((int)blockIdx.x * 2 + g2) * 2 + o] = acc;
    }
}

extern "C" void kernel_launch(void* const* d_in, const int* in_sizes, int n_in,
                              void* d_out, int out_size, void* d_ws, size_t ws_size,
                              hipStream_t stream) {
    const float* x      = (const float*)d_in[0];
    const float* w_ih   = (const float*)d_in[1];
    const float* w_hh   = (const float*)d_in[2];
    const float* b_ih   = (const float*)d_in[3];
    const float* b_hh   = (const float*)d_in[4];
    const float* head_w = (const float*)d_in[5];
    const float* head_b = (const float*)d_in[6];
    float* out = (float*)d_out;

    const int B = out_size / 2;          // O = 2
    const int T = in_sizes[0] / B;       // x is [B,T]

    dim3 grid(B / 2), block(64);
    hipLaunchKernelGGL(gru_scan_kernel, grid, block, 0, stream,
                       x, w_ih, w_hh, b_ih, b_hh, head_w, head_b, out, T);
}

// Round 12
// 508.872 us; speedup vs baseline: 1.2655x; 1.2655x over previous
//
#include <hip/hip_runtime.h>

// SimpleGRU scan: B=2048 seqs, T=2048 steps, H=32, O=2, fp32 backbone.
// Round-12: revert to R8 (best, 465us) + the three micro-wins that survived
// all post-mortems. Measured structure of R8: wall 525 cyc/step-pair =
// 192 (MAC issue floor: 96 MACs/lane @ 2cyc/MAC, encoding-independent --
// fdot2/pk_fma_f16/pk_fma_f32/scalar all measured equal R7/R9) + ~100
// act/glue + ~60 allocator residual (pin attempts R3/R10 backfired) + ~173
// exchange exposure (R11 proved crossbar gather worse; R5 proved split-K
// TLP eats its gain; lockstep lanes can't skew). This round:
//  1. 4x4 dot chains (R10's fix 2, WITHOUT the in-loop pin): -25cyc dep tail.
//  2. direct-rcp sigmoids (R11): shorter r critical path.
//  3. x in registers (R7): float4 dbuf global loads, 4-step loop unrolled
//     (component selects free) -> deletes x LDS staging + chunk barriers.

typedef _Float16 f16x2 __attribute__((ext_vector_type(2)));

__device__ __forceinline__ float fdot2(int a, int b, float c) {
    return __builtin_amdgcn_fdot2(__builtin_bit_cast(f16x2, a),
                                  __builtin_bit_cast(f16x2, b), c, false);
}

__device__ __forceinline__ int pack_pair(float a, float b) {
    f16x2 p;
    p.x = (_Float16)a;
    p.y = (_Float16)b;
    return __builtin_bit_cast(int, p);
}

__global__ __launch_bounds__(64, 1)
void gru_scan_kernel(const float* __restrict__ x,      // [B,T]
                     const float* __restrict__ w_ih,   // [96,1]
                     const float* __restrict__ w_hh,   // [96,32]
                     const float* __restrict__ b_ih,   // [96]
                     const float* __restrict__ b_hh,   // [96]
                     const float* __restrict__ head_w, // [2,32]
                     const float* __restrict__ head_b, // [2]
                     float* __restrict__ out,          // [B,2]
                     int T)
{
    const int l = (int)threadIdx.x;
    const int g = l >> 5;   // batch slot within wave
    const int j = l & 31;   // gate/hidden row
    const int b = (int)blockIdx.x * 2 + g;

    __shared__ __align__(16) _Float16 h16[2][32];   // [group][hidden] f16
    __shared__ float hf_s[2][32];                   // fp32 h for head

    // ---- per-lane weights: rows j (r), 32+j (z), 64+j (n), full K=32,
    // as 16 f16x2 pairs per gate = 48 int regs, one-time pin (R8 config) ----
    int wR[16], wZ[16], wN[16];
    {
        const float* pR = w_hh + (     j) * 32;
        const float* pZ = w_hh + (32 + j) * 32;
        const float* pN = w_hh + (64 + j) * 32;
#pragma unroll
        for (int q = 0; q < 16; ++q) {
            wR[q] = pack_pair(pR[2*q], pR[2*q+1]);
            wZ[q] = pack_pair(pZ[2*q], pZ[2*q+1]);
            wN[q] = pack_pair(pN[2*q], pN[2*q+1]);
        }
    }
#pragma unroll
    for (int q = 0; q < 16; ++q) {
        asm volatile("" : "+v"(wR[q]), "+v"(wZ[q]), "+v"(wN[q]));
    }

    // full-K: every lane computes complete dots -> plain per-row seeds
    const float wihr = w_ih[j];
    const float wihz = w_ih[32 + j];
    const float wihn = w_ih[64 + j];
    const float br   = b_ih[j]      + b_hh[j];
    const float bz   = b_ih[32 + j] + b_hh[32 + j];
    const float bni  = b_ih[64 + j];
    const float bnh  = b_hh[64 + j];

    const float*  xrow  = x + (size_t)b * (size_t)T;
    const float4* xrow4 = (const float4*)xrow;     // T=2048 -> 16B aligned
    const int     n4    = T >> 2;                  // 512 groups of 4 steps
    const int     t4max = n4 - 1;

    float h = 0.0f;
    h16[g][j] = (_Float16)0.0f;
    __builtin_amdgcn_wave_barrier();

    // own group's 32 h = 64 B = 4 broadcast b128 reads (group-disjoint banks)
    const int4* hq = (const int4*)(&h16[g][0]);

    float4 xcur = xrow4[0];
    float4 xnxt = xrow4[1 <= t4max ? 1 : 0];

    for (int t4 = 0; t4 < n4; ++t4) {
        const float4 xg = xcur;
        xcur = xnxt;
        const int nidx = (t4 + 2 <= t4max) ? (t4 + 2) : t4max;
        xnxt = xrow4[nidx];              // consumed 4 steps later: hidden
#pragma unroll
        for (int s = 0; s < 4; ++s) {
            const float xv = (s == 0) ? xg.x : (s == 1) ? xg.y
                           : (s == 2) ? xg.z : xg.w;   // free after unroll
            const int4 H0 = hq[0];   // h pairs 0..3
            const int4 H1 = hq[1];   // pairs 4..7
            const int4 H2 = hq[2];   // pairs 8..11
            const int4 H3 = hq[3];   // pairs 12..15

            // 4 chains of 4 dot2 per gate (16 pairs = full K=32)
            float rA = fdot2(H0.x, wR[ 0], fmaf(xv, wihr, br));
            float zA = fdot2(H0.x, wZ[ 0], fmaf(xv, wihz, bz));
            float nA = fdot2(H0.x, wN[ 0], bnh);
            rA = fdot2(H0.y, wR[ 1], rA); zA = fdot2(H0.y, wZ[ 1], zA); nA = fdot2(H0.y, wN[ 1], nA);
            rA = fdot2(H0.z, wR[ 2], rA); zA = fdot2(H0.z, wZ[ 2], zA); nA = fdot2(H0.z, wN[ 2], nA);
            rA = fdot2(H0.w, wR[ 3], rA); zA = fdot2(H0.w, wZ[ 3], zA); nA = fdot2(H0.w, wN[ 3], nA);

            float rB = fdot2(H1.x, wR[ 4], 0.0f);
            float zB = fdot2(H1.x, wZ[ 4], 0.0f);
            float nB = fdot2(H1.x, wN[ 4], 0.0f);
            rB = fdot2(H1.y, wR[ 5], rB); zB = fdot2(H1.y, wZ[ 5], zB); nB = fdot2(H1.y, wN[ 5], nB);
            rB = fdot2(H1.z, wR[ 6], rB); zB = fdot2(H1.z, wZ[ 6], zB); nB = fdot2(H1.z, wN[ 6], nB);
            rB = fdot2(H1.w, wR[ 7], rB); zB = fdot2(H1.w, wZ[ 7], zB); nB = fdot2(H1.w, wN[ 7], nB);

            float rC = fdot2(H2.x, wR[ 8], 0.0f);
            float zC = fdot2(H2.x, wZ[ 8], 0.0f);
            float nC = fdot2(H2.x, wN[ 8], 0.0f);
            rC = fdot2(H2.y, wR[ 9], rC); zC = fdot2(H2.y, wZ[ 9], zC); nC = fdot2(H2.y, wN[ 9], nC);
            rC = fdot2(H2.z, wR[10], rC); zC = fdot2(H2.z, wZ[10], zC); nC = fdot2(H2.z, wN[10], nC);
            rC = fdot2(H2.w, wR[11], rC); zC = fdot2(H2.w, wZ[11], zC); nC = fdot2(H2.w, wN[11], nC);

            float rD = fdot2(H3.x, wR[12], 0.0f);
            float zD = fdot2(H3.x, wZ[12], 0.0f);
            float nD = fdot2(H3.x, wN[12], 0.0f);
            rD = fdot2(H3.y, wR[13], rD); zD = fdot2(H3.y, wZ[13], zD); nD = fdot2(H3.y, wN[13], nD);
            rD = fdot2(H3.z, wR[14], rD); zD = fdot2(H3.z, wZ[14], zD); nD = fdot2(H3.z, wN[14], nD);
            rD = fdot2(H3.w, wR[15], rD); zD = fdot2(H3.w, wZ[15], zD); nD = fdot2(H3.w, wN[15], nD);

            const float rp = (rA + rB) + (rC + rD);
            const float zp = (zA + zB) + (zC + zD);
            const float np = (nA + nB) + (nC + nD);

            // direct-rcp sigmoids (r is on the critical path; z is late)
            const float er = __builtin_amdgcn_exp2f(rp * -1.44269504088896f);
            const float r  = __builtin_amdgcn_rcpf(1.0f + er);
            const float ez = __builtin_amdgcn_exp2f(zp * -1.44269504088896f);
            const float z  = __builtin_amdgcn_rcpf(1.0f + ez);

            // n = tanh(xn + r*np)
            const float xn = fmaf(xv, wihn, bni);
            const float u  = fmaf(r, np, xn);
            const float et = __builtin_amdgcn_exp2f(u * 2.88539008177793f);
            const float ti = __builtin_amdgcn_rcpf(1.0f + et);
            const float n  = fmaf(-2.0f, ti, 1.0f);

            h = fmaf(z, h - n, n);                   // (1-z)*n + z*h
            __builtin_amdgcn_wave_barrier();
            h16[g][j] = (_Float16)h;                 // publish for next step
            __builtin_amdgcn_wave_barrier();         // in-order DS => RAW safe
        }
    }

    // ---- head: out[b,o] = head_b[o] + sum_k h[k]*head_w[o,k] (fp32 h) ----
    hf_s[g][j] = h;
    __builtin_amdgcn_wave_barrier();
    if (l < 4) {
        const int g2 = l >> 1, o = l & 1;
        float acc = head_b[o];
        const float* hw = head_w + o * 32;
#pragma unroll
        for (int k = 0; k < 32; ++k) acc = fmaf(hf_s[g2][k], hw[k], acc);
        out[((int)blockIdx.x * 2 + g2) * 2 + o] = acc;
    }
}

extern "C" void kernel_launch(void* const* d_in, const int* in_sizes, int n_in,
                              void* d_out, int out_size, void* d_ws, size_t ws_size,
                              hipStream_t stream) {
    const float* x      = (const float*)d_in[0];
    const float* w_ih   = (const float*)d_in[1];
    const float* w_hh   = (const float*)d_in[2];
    const float* b_ih   = (const float*)d_in[3];
    const float* b_hh   = (const float*)d_in[4];
    const float* head_w = (const float*)d_in[5];
    const float* head_b = (const float*)d_in[6];
    float* out = (float*)d_out;

    const int B = out_size / 2;          // O = 2
    const int T = in_sizes[0] / B;       // x is [B,T]

    dim3 grid(B / 2), block(64);
    hipLaunchKernelGGL(gru_scan_kernel, grid, block, 0, stream,
                       x, w_ih, w_hh, b_ih, b_hh, head_w, head_b, out, T);
}